// Round 2
// baseline (31.068 us; speedup 1.0000x reference)
//
#include <hip/hip_runtime.h>
#include <limits.h>

// Problem constants (match reference setup_inputs)
constexpr int B = 8;
constexpr int L = 4096;
constexpr int D = 1024;
constexpr int S = 128;
constexpr int P = L - 64;   // 4032

// One block per (batch, sentence). 256 threads; each thread owns one float4
// column (D/4 = 256). subword2sents is sorted per batch, so the token range
// for sentence s is [lower_bound(s), lower_bound(s+1)).
//
// Boundary discovery: cooperative transition scan (16 independent coalesced
// load rounds) instead of a binary search (24 *dependent* scalar loads).
// The unique index i with row[i-1] < v <= row[i] is lower_bound(v).
__global__ __launch_bounds__(256)
void word2sent_pool_kernel(const float* __restrict__ words_emb,
                           const int* __restrict__ bounds,
                           const int* __restrict__ s2s,
                           float* __restrict__ out)
{
    const int blk = blockIdx.x;      // b*S + s
    const int b = blk >> 7;          // / S (S == 128)
    const int s = blk & (S - 1);
    const int tid = threadIdx.x;

    const int* __restrict__ row = s2s + b * P;

    __shared__ int sh_start, sh_end;
    if (tid == 0) { sh_start = P; sh_end = P; }   // defaults: all ids < v -> P
    __syncthreads();

    const int s1 = s + 1;
    for (int i = tid; i < P; i += 256) {
        const int cur  = row[i];
        const int prev = (i == 0) ? INT_MIN : row[i - 1];
        if (prev < s  && cur >= s )  sh_start = i;   // lower_bound(s)
        if (prev < s1 && cur >= s1)  sh_end   = i;   // lower_bound(s+1)
    }
    __syncthreads();

    const int start = sh_start;
    const int cnt   = sh_end - start;

    const int q0 = bounds[b * 2];    // passage start (dynamic slice offset)

    const float4* __restrict__ base = reinterpret_cast<const float4*>(
        words_emb + ((size_t)b * L + (size_t)q0 + (size_t)start) * D);

    const int d4 = tid;              // 0..255 -> float4 column
    const int rowstride = D / 4;     // 256 float4 per token row

    float4 acc = make_float4(0.f, 0.f, 0.f, 0.f);
    #pragma unroll 8
    for (int t = 0; t < cnt; ++t) {
        float4 v = base[(size_t)t * rowstride + d4];
        acc.x += v.x; acc.y += v.y; acc.z += v.z; acc.w += v.w;
    }

    const float inv = 1.0f / (float)(cnt > 0 ? cnt : 1);
    float4 r = make_float4(acc.x * inv, acc.y * inv, acc.z * inv, acc.w * inv);

    reinterpret_cast<float4*>(out)[(size_t)blk * rowstride + d4] = r;
}

extern "C" void kernel_launch(void* const* d_in, const int* in_sizes, int n_in,
                              void* d_out, int out_size, void* d_ws, size_t ws_size,
                              hipStream_t stream) {
    const float* words_emb = (const float*)d_in[0];   // [B, L, D] f32
    const int* bounds      = (const int*)d_in[1];     // [B, 2] i32
    const int* s2s         = (const int*)d_in[2];     // [B, P] i32 (sorted per row)
    float* out             = (float*)d_out;           // [B, S, D] f32

    dim3 grid(B * S);
    dim3 block(256);
    word2sent_pool_kernel<<<grid, block, 0, stream>>>(words_emb, bounds, s2s, out);
}

// Round 4
// 26.885 us; speedup vs baseline: 1.1556x; 1.1556x over previous
//
#include <hip/hip_runtime.h>

// Problem constants (match reference setup_inputs)
constexpr int B = 8;
constexpr int L = 4096;
constexpr int D = 1024;
constexpr int S = 128;
constexpr int P = L - 64;   // 4032

// Native vector type: __builtin_nontemporal_load/store accepts ext_vector,
// not HIP_vector_type<float,4>.
typedef float f32x4 __attribute__((ext_vector_type(4)));

// One block per (batch, sentence). 256 threads; each thread owns one f32x4
// column (D/4 = 256). subword2sents is sorted per batch, so the token range
// for sentence s is [lower_bound(s), lower_bound(s+1)).
//
// Boundary discovery: wave-parallel 64-ary search = 2 dependent load rounds
// (vs ~20 for scalar binary search). Wave 0 finds lower_bound(s), wave 1
// finds lower_bound(s+1) concurrently.
__global__ __launch_bounds__(256)
void word2sent_pool_kernel(const float* __restrict__ words_emb,
                           const int* __restrict__ bounds,
                           const int* __restrict__ s2s,
                           float* __restrict__ out)
{
    const int blk = blockIdx.x;      // b*S + s
    const int b = blk >> 7;          // / S (S == 128)
    const int s = blk & (S - 1);
    const int tid = threadIdx.x;
    const int wave = tid >> 6;
    const int lane = tid & 63;

    const int* __restrict__ row = s2s + b * P;

    __shared__ int sh_bound[2];      // [0]=lower_bound(s), [1]=lower_bound(s+1)

    if (wave < 2) {
        const int v = s + wave;
        // Round 1: probe row[lane*63], lane = 0..63 (max 3969 < P).
        // c = #probes < v  ->  lower_bound in ((c-1)*63, c*63].
        const int p1 = row[lane * 63];
        const unsigned long long m1 = __ballot(p1 < v);
        const int c = __popcll(m1);
        const int base = (c == 0) ? 0 : (c - 1) * 63 + 1;
        // Round 2: probe the 63-wide window exactly.
        const int pos = base + lane;
        int pred2 = 0;
        if (lane < 63 && pos < P) pred2 = (row[pos] < v) ? 1 : 0;
        const unsigned long long m2 = __ballot(pred2);
        if (lane == 0) sh_bound[wave] = base + __popcll(m2);
    }
    __syncthreads();

    const int start = sh_bound[0];
    const int cnt   = sh_bound[1] - start;

    const int q0 = bounds[b * 2];    // passage start (dynamic slice offset)

    const f32x4* __restrict__ base4 = reinterpret_cast<const f32x4*>(
        words_emb + ((size_t)b * L + (size_t)q0 + (size_t)start) * D);

    const int d4 = tid;              // 0..255 -> f32x4 column
    const int rowstride = D / 4;     // 256 f32x4 per token row

    f32x4 acc = (f32x4)(0.f);
    #pragma unroll 8
    for (int t = 0; t < cnt; ++t) {
        // read-once stream: keep it out of L2 (s2s probes stay cached)
        f32x4 v = __builtin_nontemporal_load(&base4[(size_t)t * rowstride + d4]);
        acc += v;
    }

    const float inv = 1.0f / (float)(cnt > 0 ? cnt : 1);
    f32x4 r = acc * inv;

    f32x4* __restrict__ out4 = reinterpret_cast<f32x4*>(out);
    __builtin_nontemporal_store(r, &out4[(size_t)blk * rowstride + d4]);
}

extern "C" void kernel_launch(void* const* d_in, const int* in_sizes, int n_in,
                              void* d_out, int out_size, void* d_ws, size_t ws_size,
                              hipStream_t stream) {
    const float* words_emb = (const float*)d_in[0];   // [B, L, D] f32
    const int* bounds      = (const int*)d_in[1];     // [B, 2] i32
    const int* s2s         = (const int*)d_in[2];     // [B, P] i32 (sorted per row)
    float* out             = (float*)d_out;           // [B, S, D] f32

    dim3 grid(B * S);
    dim3 block(256);
    word2sent_pool_kernel<<<grid, block, 0, stream>>>(words_emb, bounds, s2s, out);
}